// Round 2
// baseline (477.854 us; speedup 1.0000x reference)
//
#include <hip/hip_runtime.h>

// y = (spikes @ V) @ U^T
// spikes: [4096, 16384] f32, V: [16384, 32] f32, U: [16384, 32] f32
// out y: [4096, 16384] f32 (268 MB). Mask inputs are dead in the reference.

#define B_DIM 4096
#define NPRE  16384
#define NPOST 16384
#define RDIM  32

// ---- phase A: z partials -------------------------------------------------
#define NC      16               // K-split chunks
#define CHUNK   (NPRE / NC)      // 1024
#define TI      128              // i per staged tile
#define NT      (CHUNK / TI)     // 8 t-steps
#define ROWS_A  64               // b-rows per block
#define PADW    (TI + 1)         // 129: stride ≡ 1 mod 32 -> conflict-free lane-strided reads
#define REDSTR  2112             // 64*33 per-slot reduction stride

// LDS: union of tile (64*129 = 8256 f) and 4 reduction slots (4*2112 = 8448 f)
#define SMEMF   8448             // 33.8 KB -> 3+ blocks/CU

__global__ __launch_bounds__(512, 6) void zpart_kernel(
    const float* __restrict__ spikes, const float* __restrict__ V,
    float* __restrict__ part)
{
    __shared__ float smem[SMEMF];

    const int tid  = threadIdx.x;
    const int wid  = tid >> 6;           // 0..7
    const int lane = tid & 63;
    const int c    = blockIdx.x;         // chunk index
    const int brow = blockIdx.y * ROWS_A;
    const size_t ibase0 = (size_t)c * CHUNK;

    float acc[RDIM];
    #pragma unroll
    for (int r = 0; r < RDIM; ++r) acc[r] = 0.f;

    const int srow = tid >> 5;           // 0..15 (16 rows per staging pass)
    const int scol = (tid & 31) * 4;     // 0..124
    const int i0   = wid * 16;           // per-wave V/i slice (wave-uniform)

    const float* sp = spikes + (size_t)brow * NPRE + ibase0;

    // prologue: issue loads for tile 0 into registers
    float4 stg[4];
    #pragma unroll
    for (int p = 0; p < 4; ++p)
        stg[p] = *reinterpret_cast<const float4*>(
            &sp[(size_t)(p * 16 + srow) * NPRE + scol]);

    for (int t = 0; t < NT; ++t) {
        // all waves finished reading the previous tile (lgkm fence at loop tail)
        __builtin_amdgcn_s_barrier();

        // write current tile (compiler inserts vmcnt wait here -> hidden under
        // the previous iteration's compute)
        #pragma unroll
        for (int p = 0; p < 4; ++p) {
            float* dst = &smem[(p * 16 + srow) * PADW + scol];
            dst[0] = stg[p].x; dst[1] = stg[p].y; dst[2] = stg[p].z; dst[3] = stg[p].w;
        }

        // issue next tile's loads NOW — they stay in flight across the barrier
        if (t + 1 < NT) {
            #pragma unroll
            for (int p = 0; p < 4; ++p)
                stg[p] = *reinterpret_cast<const float4*>(
                    &sp[(size_t)(p * 16 + srow) * NPRE + (size_t)(t + 1) * TI + scol]);
        }

        asm volatile("s_waitcnt lgkmcnt(0)" ::: "memory");  // ds_writes visible
        __builtin_amdgcn_s_barrier();

        // compute: 16 i per wave, 32 fmac each; V via wave-uniform s_loads
        const float* vbase = &V[(ibase0 + (size_t)t * TI + i0) * RDIM];
        #pragma unroll
        for (int ii = 0; ii < 16; ++ii) {
            const float s = smem[lane * PADW + i0 + ii];
            #pragma unroll
            for (int r = 0; r < RDIM; ++r)
                acc[r] = fmaf(s, vbase[ii * RDIM + r], acc[r]);
        }
        asm volatile("s_waitcnt lgkmcnt(0)" ::: "memory");  // reads drained before overwrite
    }

    // ---- cross-wave reduction: 8 partials -> 4 slots -> final sum ----
    __syncthreads();
    if (wid < 4) {
        #pragma unroll
        for (int r = 0; r < RDIM; ++r)
            smem[wid * REDSTR + lane * 33 + r] = acc[r];
    }
    __syncthreads();
    if (wid >= 4) {
        #pragma unroll
        for (int r = 0; r < RDIM; ++r)
            smem[(wid - 4) * REDSTR + lane * 33 + r] += acc[r];
    }
    __syncthreads();
    {
        const int p  = tid * 4;          // 2048 outputs = 64 rows x 32 r
        const int b  = p >> 5;
        const int r0 = p & 31;
        float sx = 0.f, sy = 0.f, sz = 0.f, sw = 0.f;
        #pragma unroll
        for (int w = 0; w < 4; ++w) {
            const float* src = &smem[w * REDSTR + b * 33 + r0];
            sx += src[0]; sy += src[1]; sz += src[2]; sw += src[3];
        }
        float4 s4; s4.x = sx; s4.y = sy; s4.z = sz; s4.w = sw;
        *reinterpret_cast<float4*>(
            &part[(size_t)c * (B_DIM * RDIM) + (size_t)(brow + b) * RDIM + r0]) = s4;
    }
}

// ---- z reduction: z[b][r] = sum_c part[c][b][r] --------------------------
__global__ void zreduce_kernel(const float* __restrict__ part, float* __restrict__ z)
{
    const int idx = (blockIdx.x * blockDim.x + threadIdx.x) * 4;  // over 131072 floats
    float sx = 0.f, sy = 0.f, sz = 0.f, sw = 0.f;
    #pragma unroll
    for (int c = 0; c < NC; ++c) {
        const float4 p = *reinterpret_cast<const float4*>(
            &part[(size_t)c * (B_DIM * RDIM) + idx]);
        sx += p.x; sy += p.y; sz += p.z; sw += p.w;
    }
    float4 s4; s4.x = sx; s4.y = sy; s4.z = sz; s4.w = sw;
    *reinterpret_cast<float4*>(&z[idx]) = s4;
}

// ---- phase B: y[b][j] = sum_r z[b][r] * U[j][r] --------------------------
#define TJ 256
#define TB 64

__global__ __launch_bounds__(256) void ykernel(
    const float* __restrict__ z, const float* __restrict__ U,
    float* __restrict__ y)
{
    const int j  = blockIdx.x * TJ + threadIdx.x;
    const int b0 = blockIdx.y * TB;

    float u[RDIM];
    #pragma unroll
    for (int q = 0; q < 8; ++q) {
        const float4 v = *reinterpret_cast<const float4*>(&U[(size_t)j * RDIM + q * 4]);
        u[q * 4 + 0] = v.x; u[q * 4 + 1] = v.y; u[q * 4 + 2] = v.z; u[q * 4 + 3] = v.w;
    }

    for (int bb = 0; bb < TB; ++bb) {
        const float* zr = &z[(size_t)(b0 + bb) * RDIM];   // wave-uniform -> s_load
        float a0 = 0.f, a1 = 0.f, a2 = 0.f, a3 = 0.f;
        #pragma unroll
        for (int r = 0; r < RDIM; r += 4) {
            a0 += zr[r + 0] * u[r + 0];
            a1 += zr[r + 1] * u[r + 1];
            a2 += zr[r + 2] * u[r + 2];
            a3 += zr[r + 3] * u[r + 3];
        }
        y[(size_t)(b0 + bb) * NPOST + j] = (a0 + a1) + (a2 + a3);
    }
}

extern "C" void kernel_launch(void* const* d_in, const int* in_sizes, int n_in,
                              void* d_out, int out_size, void* d_ws, size_t ws_size,
                              hipStream_t stream)
{
    const float* spikes = (const float*)d_in[0];   // [4096, 16384]
    const float* U      = (const float*)d_in[1];   // [16384, 32]
    const float* V      = (const float*)d_in[2];   // [16384, 32]
    float* y    = (float*)d_out;
    float* part = (float*)d_out;                   // first 8 MB of d_out, consumed before y overwrites
    float* z    = (float*)d_ws;                    // 512 KB scratch

    zpart_kernel<<<dim3(NC, B_DIM / ROWS_A), 512, 0, stream>>>(spikes, V, part);
    zreduce_kernel<<<dim3((B_DIM * RDIM / 4) / 256), 256, 0, stream>>>(part, z);
    ykernel<<<dim3(NPOST / TJ, B_DIM / TB), 256, 0, stream>>>(z, U, y);
}

// Round 3
// 203.495 us; speedup vs baseline: 2.3482x; 2.3482x over previous
//
#include <hip/hip_runtime.h>

// y = (spikes @ V) @ U^T
// spikes: [4096, 16384] f32, V: [16384, 32] f32, U: [16384, 32] f32
// out y: [4096, 16384] f32 (268 MB). Mask inputs are dead in the reference.

#define B_DIM 4096
#define NPRE  16384
#define NPOST 16384
#define RDIM  32

// ---- phase A: z partials -------------------------------------------------
#define NC     16
#define CHUNK  (NPRE / NC)     // 1024
#define TI     128             // columns per staged tile
#define NT     (CHUNK / TI)    // 8 pipeline steps
#define ROWS_A 64              // b-rows per block
#define TILEF  (ROWS_A * TI)   // 8192 floats = 32 KB per buffer
#define REDSTR 2112            // 64*33 per-slot reduction stride (4 slots = 8448 f <= 16384)

typedef const __attribute__((address_space(1))) void GAS;
typedef __attribute__((address_space(3))) void LAS;

__global__ __launch_bounds__(512, 2) void zpart_kernel(
    const float* __restrict__ spikes, const float* __restrict__ V,
    float* __restrict__ part)
{
    __shared__ float smem[2 * TILEF];   // 64 KB -> 2 blocks/CU

    const int tid  = threadIdx.x;
    const int wid  = tid >> 6;          // 0..7
    const int lane = tid & 63;
    const int c    = blockIdx.x;
    const int brow = blockIdx.y * ROWS_A;
    const size_t ibase0 = (size_t)c * CHUNK;

    float acc[RDIM];
    #pragma unroll
    for (int r = 0; r < RDIM; ++r) acc[r] = 0.f;

    const int i0  = __builtin_amdgcn_readfirstlane(wid * 16); // wave's 16-col slice
    const int i04 = i0 >> 2;                                  // granule base (wid*4)

    // Staging: 4 global_load_lds(16B) per wave; instr p covers rows wid*8+p*2(+lane>>5).
    // LDS is written lane-linear => realize the XOR-swizzled layout by PRE-SWIZZLING
    // the global source column: stored[row][c4] = orig[row][c4 ^ (row&31)].
    const float* gsrc[4];
    #pragma unroll
    for (int p = 0; p < 4; ++p) {
        const int row = wid * 8 + p * 2 + (lane >> 5);
        const int c4s = (lane & 31) ^ (row & 31);
        gsrc[p] = spikes + (size_t)(brow + row) * NPRE + ibase0 + (c4s << 2);
    }

    // prologue: stage tile 0 into buf 0
    #pragma unroll
    for (int p = 0; p < 4; ++p)
        __builtin_amdgcn_global_load_lds((GAS*)gsrc[p],
            (LAS*)&smem[(wid * 8 + p * 2) * TI], 16, 0, 0);
    __syncthreads();

    int cur = 0;
    for (int t = 0; t < NT; ++t) {
        // issue next tile's DMA now; it flies under this tile's compute
        if (t + 1 < NT) {
            const int nxt = cur ^ 1;
            #pragma unroll
            for (int p = 0; p < 4; ++p)
                __builtin_amdgcn_global_load_lds((GAS*)(gsrc[p] + (size_t)(t + 1) * TI),
                    (LAS*)&smem[nxt * TILEF + (wid * 8 + p * 2) * TI], 16, 0, 0);
        }

        // compute: lane owns row=lane; 4 granules x (4 cols x 32 fmac), V via s_load
        const float* vb = V + (ibase0 + (size_t)t * TI + i0) * RDIM;
        const float* sb = &smem[cur * TILEF + lane * TI];
        #pragma unroll
        for (int g = 0; g < 4; ++g) {
            const int c4 = i04 + g;
            const float4 s4 = *reinterpret_cast<const float4*>(
                &sb[(c4 ^ (lane & 31)) << 2]);       // same XOR -> original cols 4c4..4c4+3
            const float sv[4] = { s4.x, s4.y, s4.z, s4.w };
            #pragma unroll
            for (int w = 0; w < 4; ++w) {
                #pragma unroll
                for (int r = 0; r < RDIM; ++r)
                    acc[r] = fmaf(sv[w], vb[(g * 4 + w) * RDIM + r], acc[r]);
            }
        }

        // __syncthreads drains vmcnt (next tile landed) + syncs waves — exactly the wait we need
        if (t + 1 < NT) __syncthreads();
        cur ^= 1;
    }

    // ---- cross-wave reduction: 8 partials -> 4 slots -> final sum ----
    __syncthreads();
    if (wid < 4) {
        #pragma unroll
        for (int r = 0; r < RDIM; ++r)
            smem[wid * REDSTR + lane * 33 + r] = acc[r];
    }
    __syncthreads();
    if (wid >= 4) {
        #pragma unroll
        for (int r = 0; r < RDIM; ++r)
            smem[(wid - 4) * REDSTR + lane * 33 + r] += acc[r];
    }
    __syncthreads();
    {
        const int p  = tid * 4;          // 2048 outputs = 64 rows x 32 r
        const int b  = p >> 5;
        const int r0 = p & 31;
        float sx = 0.f, sy = 0.f, sz = 0.f, sw = 0.f;
        #pragma unroll
        for (int w = 0; w < 4; ++w) {
            const float* src = &smem[w * REDSTR + b * 33 + r0];
            sx += src[0]; sy += src[1]; sz += src[2]; sw += src[3];
        }
        float4 s4; s4.x = sx; s4.y = sy; s4.z = sz; s4.w = sw;
        *reinterpret_cast<float4*>(
            &part[(size_t)c * (B_DIM * RDIM) + (size_t)(brow + b) * RDIM + r0]) = s4;
    }
}

// ---- z reduction: z[b][r] = sum_c part[c][b][r] --------------------------
__global__ void zreduce_kernel(const float* __restrict__ part, float* __restrict__ z)
{
    const int idx = (blockIdx.x * blockDim.x + threadIdx.x) * 4;  // over 131072 floats
    float sx = 0.f, sy = 0.f, sz = 0.f, sw = 0.f;
    #pragma unroll
    for (int c = 0; c < NC; ++c) {
        const float4 p = *reinterpret_cast<const float4*>(
            &part[(size_t)c * (B_DIM * RDIM) + idx]);
        sx += p.x; sy += p.y; sz += p.z; sw += p.w;
    }
    float4 s4; s4.x = sx; s4.y = sy; s4.z = sz; s4.w = sw;
    *reinterpret_cast<float4*>(&z[idx]) = s4;
}

// ---- phase B: y[b][j] = sum_r z[b][r] * U[j][r] --------------------------
#define TJ 256
#define TB 64

__global__ __launch_bounds__(256) void ykernel(
    const float* __restrict__ z, const float* __restrict__ U,
    float* __restrict__ y)
{
    const int j  = blockIdx.x * TJ + threadIdx.x;
    const int b0 = blockIdx.y * TB;

    float u[RDIM];
    #pragma unroll
    for (int q = 0; q < 8; ++q) {
        const float4 v = *reinterpret_cast<const float4*>(&U[(size_t)j * RDIM + q * 4]);
        u[q * 4 + 0] = v.x; u[q * 4 + 1] = v.y; u[q * 4 + 2] = v.z; u[q * 4 + 3] = v.w;
    }

    for (int bb = 0; bb < TB; ++bb) {
        const float* zr = &z[(size_t)(b0 + bb) * RDIM];   // wave-uniform -> s_load
        float a0 = 0.f, a1 = 0.f, a2 = 0.f, a3 = 0.f;
        #pragma unroll
        for (int r = 0; r < RDIM; r += 4) {
            a0 += zr[r + 0] * u[r + 0];
            a1 += zr[r + 1] * u[r + 1];
            a2 += zr[r + 2] * u[r + 2];
            a3 += zr[r + 3] * u[r + 3];
        }
        y[(size_t)(b0 + bb) * NPOST + j] = (a0 + a1) + (a2 + a3);
    }
}

extern "C" void kernel_launch(void* const* d_in, const int* in_sizes, int n_in,
                              void* d_out, int out_size, void* d_ws, size_t ws_size,
                              hipStream_t stream)
{
    const float* spikes = (const float*)d_in[0];   // [4096, 16384]
    const float* U      = (const float*)d_in[1];   // [16384, 32]
    const float* V      = (const float*)d_in[2];   // [16384, 32]
    float* y    = (float*)d_out;
    float* part = (float*)d_out;                   // first 8 MB of d_out, consumed before y overwrites
    float* z    = (float*)d_ws;                    // 512 KB scratch

    zpart_kernel<<<dim3(NC, B_DIM / ROWS_A), 512, 0, stream>>>(spikes, V, part);
    zreduce_kernel<<<dim3((B_DIM * RDIM / 4) / 256), 256, 0, stream>>>(part, z);
    ykernel<<<dim3(NPOST / TJ, B_DIM / TB), 256, 0, stream>>>(z, U, y);
}

// Round 4
// 170.389 us; speedup vs baseline: 2.8045x; 1.1943x over previous
//
#include <hip/hip_runtime.h>
#include <hip/hip_bf16.h>

// y = (spikes @ V) @ U^T
// spikes: [4096, 16384] f32, V: [16384, 32] f32, U: [16384, 32] f32
// y: [4096, 16384] f32 (268 MB). Mask inputs are dead in the reference.
//
// Phase A (z = spikes@V) via bf16 MFMA 16x16x32, K-split into NC chunks.
// V is pre-packed to bf16 in MFMA B-fragment order (1 MB, L2-resident), so the
// entire V operand per k-step is two coalesced 16B loads — this removes the
// per-lane V-load latency serialization that bounded rounds 1-3.

#define B_DIM 4096
#define NPRE  16384
#define NPOST 16384
#define RDIM  32

#define NC     16                      // K-split chunks
#define CHUNK  (NPRE / NC)             // 1024
#define KSTEPS (CHUNK / 32)            // 32 mfma k-steps per wave

typedef __attribute__((ext_vector_type(8))) short short8;   // 8 bf16 = 4 VGPRs
typedef __attribute__((ext_vector_type(4))) float f32x4;

static __device__ __forceinline__ unsigned pack_bf2(float lo, float hi) {
    union { __hip_bfloat162 h; unsigned u; } c;
    c.h = __float22bfloat162_rn(make_float2(lo, hi));   // v_cvt_pk_bf16_f32
    return c.u;
}

// ---- V packing: vpack[((kt*2+half)*64 + lane)*8 + e] = bf16(V[kt*32+(lane>>4)*8+e][half*16+(lane&15)])
__global__ void vpack_kernel(const float* __restrict__ V, short* __restrict__ vpack)
{
    const int tid  = blockIdx.x * 256 + threadIdx.x;   // 65536 = 512 kt * 2 half * 64 lane
    const int lane = tid & 63;
    const int half = (tid >> 6) & 1;
    const int kt   = tid >> 7;
    const int n    = half * 16 + (lane & 15);
    const int k0   = kt * 32 + (lane >> 4) * 8;
    union { short8 s; short el[8]; } f;
    #pragma unroll
    for (int e = 0; e < 8; ++e) {
        union { __hip_bfloat16 h; short s; } c;
        c.h = __float2bfloat16(V[(size_t)(k0 + e) * RDIM + n]);
        f.el[e] = c.s;
    }
    *reinterpret_cast<short8*>(vpack + (size_t)tid * 8) = f.s;
}

// ---- phase A: one wave = one (16-row strip, 1024-k chunk) partial ----------
__global__ __launch_bounds__(256) void zpart_kernel(
    const float* __restrict__ spikes, const short* __restrict__ vpack,
    float* __restrict__ part)
{
    const int lane   = threadIdx.x & 63;
    const int widx   = threadIdx.x >> 6;
    const int bstrip = blockIdx.x >> 2;                 // 0..255
    const int kc     = ((blockIdx.x & 3) << 2) | widx;  // 0..15

    const int m  = lane & 15;     // A row within strip  (A: m = lane&15)
    const int kg = lane >> 4;     // k-group, 8 k each   (A: k = kg*8 + e)

    const float* arow  = spikes + (size_t)(bstrip * 16 + m) * NPRE
                                + (size_t)kc * CHUNK + kg * 8;
    const short* bbase = vpack + (size_t)(kc * KSTEPS) * 1024;  // 2 frags * 64 lanes * 8

    f32x4 acc0 = {0.f, 0.f, 0.f, 0.f};
    f32x4 acc1 = {0.f, 0.f, 0.f, 0.f};

    // prologue: k-step 0 operands
    f32x4 al = *reinterpret_cast<const f32x4*>(arow);
    f32x4 ah = *reinterpret_cast<const f32x4*>(arow + 4);
    short8 b0 = *reinterpret_cast<const short8*>(bbase + lane * 8);
    short8 b1 = *reinterpret_cast<const short8*>(bbase + 512 + lane * 8);

    #pragma unroll
    for (int kt = 0; kt < KSTEPS; ++kt) {
        f32x4 nal, nah; short8 nb0, nb1;
        if (kt + 1 < KSTEPS) {          // issue next step's loads before MFMAs
            nal = *reinterpret_cast<const f32x4*>(arow + (kt + 1) * 32);
            nah = *reinterpret_cast<const f32x4*>(arow + (kt + 1) * 32 + 4);
            nb0 = *reinterpret_cast<const short8*>(bbase + (kt + 1) * 1024 + lane * 8);
            nb1 = *reinterpret_cast<const short8*>(bbase + (kt + 1) * 1024 + 512 + lane * 8);
        }
        union { short8 s; unsigned u[4]; } af;
        af.u[0] = pack_bf2(al.x, al.y);
        af.u[1] = pack_bf2(al.z, al.w);
        af.u[2] = pack_bf2(ah.x, ah.y);
        af.u[3] = pack_bf2(ah.z, ah.w);
        acc0 = __builtin_amdgcn_mfma_f32_16x16x32_bf16(af.s, b0, acc0, 0, 0, 0);
        acc1 = __builtin_amdgcn_mfma_f32_16x16x32_bf16(af.s, b1, acc1, 0, 0, 0);
        al = nal; ah = nah; b0 = nb0; b1 = nb1;
    }

    // C layout: n = lane&15, m = (lane>>4)*4 + j   -> part[kc][bstrip*16+m][r]
    float* pout = part + ((size_t)kc * B_DIM + bstrip * 16) * RDIM;
    #pragma unroll
    for (int j = 0; j < 4; ++j) {
        const int row = kg * 4 + j;
        pout[row * RDIM + (lane & 15)]      = acc0[j];
        pout[row * RDIM + 16 + (lane & 15)] = acc1[j];
    }
}

// ---- z reduction: z[b][r] = sum_c part[c][b][r] ---------------------------
__global__ void zreduce_kernel(const float* __restrict__ part, float* __restrict__ z)
{
    const int idx = (blockIdx.x * blockDim.x + threadIdx.x) * 4;  // 131072 floats
    float sx = 0.f, sy = 0.f, sz = 0.f, sw = 0.f;
    #pragma unroll
    for (int c = 0; c < NC; ++c) {
        const float4 p = *reinterpret_cast<const float4*>(
            &part[(size_t)c * (B_DIM * RDIM) + idx]);
        sx += p.x; sy += p.y; sz += p.z; sw += p.w;
    }
    float4 s4; s4.x = sx; s4.y = sy; s4.z = sz; s4.w = sw;
    *reinterpret_cast<float4*>(&z[idx]) = s4;
}

// ---- phase B: y[b][j] = sum_r z[b][r] * U[j][r] ---------------------------
#define TJ 256
#define TB 64

__global__ __launch_bounds__(256) void ykernel(
    const float* __restrict__ z, const float* __restrict__ U,
    float* __restrict__ y)
{
    const int j  = blockIdx.x * TJ + threadIdx.x;
    const int b0 = blockIdx.y * TB;

    float u[RDIM];
    #pragma unroll
    for (int q = 0; q < 8; ++q) {
        const float4 v = *reinterpret_cast<const float4*>(&U[(size_t)j * RDIM + q * 4]);
        u[q * 4 + 0] = v.x; u[q * 4 + 1] = v.y; u[q * 4 + 2] = v.z; u[q * 4 + 3] = v.w;
    }

    for (int bb = 0; bb < TB; ++bb) {
        const float* zr = &z[(size_t)(b0 + bb) * RDIM];
        float a0 = 0.f, a1 = 0.f, a2 = 0.f, a3 = 0.f;
        #pragma unroll
        for (int r = 0; r < RDIM; r += 4) {
            a0 += zr[r + 0] * u[r + 0];
            a1 += zr[r + 1] * u[r + 1];
            a2 += zr[r + 2] * u[r + 2];
            a3 += zr[r + 3] * u[r + 3];
        }
        y[(size_t)(b0 + bb) * NPOST + j] = (a0 + a1) + (a2 + a3);
    }
}

extern "C" void kernel_launch(void* const* d_in, const int* in_sizes, int n_in,
                              void* d_out, int out_size, void* d_ws, size_t ws_size,
                              hipStream_t stream)
{
    const float* spikes = (const float*)d_in[0];   // [4096, 16384]
    const float* U      = (const float*)d_in[1];   // [16384, 32]
    const float* V      = (const float*)d_in[2];   // [16384, 32]

    float* y     = (float*)d_out;
    float* part  = (float*)d_out;                         // [16][4096][32] f32 = 8 MB
    short* vpack = (short*)((float*)d_out + (size_t)NC * B_DIM * RDIM);  // 1 MB after partials
    float* z     = (float*)d_ws;                          // 512 KB

    vpack_kernel<<<256, 256, 0, stream>>>(V, vpack);
    zpart_kernel<<<dim3(1024), 256, 0, stream>>>(spikes, vpack, part);
    zreduce_kernel<<<dim3((B_DIM * RDIM / 4) / 256), 256, 0, stream>>>(part, z);
    ykernel<<<dim3(NPOST / TJ, B_DIM / TB), 256, 0, stream>>>(z, U, y);
}